// Round 7
// baseline (37.750 us; speedup 1.0000x reference)
//
#include <hip/hip_runtime.h>

constexpr int NPTS  = 1024;   // points per batch
constexpr int NT    = 21;     // targets per batch
constexpr int KSEL  = 64;     // top-k
constexpr int BLOCK = 256;    // 4 waves, 1 wave per (b,t)
constexpr int PPL   = 16;     // points per lane (1024 / 64)
constexpr int NXCD  = 8;

typedef float f32x4 __attribute__((ext_vector_type(4)));

__device__ __forceinline__ unsigned key_of(float d) {
    // monotone float->uint transform (total order matching float <)
    unsigned u = __float_as_uint(d);
    return (u & 0x80000000u) ? ~u : (u | 0x80000000u);
}

__device__ __forceinline__ unsigned mbcnt64(unsigned long long m) {
    unsigned lo = __builtin_amdgcn_mbcnt_lo((unsigned)m, 0u);
    return __builtin_amdgcn_mbcnt_hi((unsigned)(m >> 32), lo);
}

__global__ __launch_bounds__(BLOCK) void knn_mask_fused_kernel(
    const float* __restrict__ pc,   // (B, 1024, 3)
    const float* __restrict__ tgt,  // (B, 21, 3)
    float* __restrict__ out,        // (B, 21, 1024, 3)
    int total_bt)
{
    const int wave = threadIdx.x >> 6;
    const int lane = threadIdx.x & 63;
    // bijective XCD swizzle (gridDim.x divisible by 8)
    const int cpx  = gridDim.x / NXCD;
    const int sbid = ((int)blockIdx.x % NXCD) * cpx + (int)blockIdx.x / NXCD;
    const int bt   = sbid * 4 + wave;
    if (bt >= total_bt) return;          // wave-uniform
    const int b  = bt / NT;
    const int tq = bt % NT;

    const float* base  = pc  + (size_t)b  * (NPTS * 3);
    float*       obase = out + (size_t)bt * (NPTS * 3);
    f32x4*       dst4  = reinterpret_cast<f32x4*>(obase);
    const f32x4  z     = {0.0f, 0.0f, 0.0f, 0.0f};

    const bool zfirst = (wave & 1) == 0;   // de-phase: half zero-first, half select-first

    // target point (wave-uniform, L1-broadcast)
    const float* tp = tgt + ((size_t)b * NT + tq) * 3;
    const float  t0 = tp[0], t1 = tp[1], t2 = tp[2];
    const float  dt = t0 * t0 + t1 * t1 + t2 * t2;

    // ---- phase 1: strided ownership (lane owns points 64*i + lane).
    // Even waves drip the 12 select-independent zero-stores into this loop
    // so store issue is steady, not a burst.
    unsigned key[PPL];
    if (zfirst) {
        #pragma unroll
        for (int i = 0; i < PPL; ++i) {
            if (i < 12) dst4[64 * i + lane] = z;
            const float* pp = base + 3 * (64 * i + lane);
            const float p0 = pp[0], p1 = pp[1], p2 = pp[2];
            const float d  = dt + (p0 * p0 + p1 * p1 + p2 * p2)
                                - 2.0f * (t0 * p0 + t1 * p1 + t2 * p2);
            key[i] = key_of(d);
        }
    } else {
        #pragma unroll
        for (int i = 0; i < PPL; ++i) {
            const float* pp = base + 3 * (64 * i + lane);
            const float p0 = pp[0], p1 = pp[1], p2 = pp[2];
            const float d  = dt + (p0 * p0 + p1 * p1 + p2 * p2)
                                - 2.0f * (t0 * p0 + t1 * p1 + t2 * p2);
            key[i] = key_of(d);
        }
    }

    // ---- phase 2: barrier-free bitwise binary search for the KSEL-th smallest
    unsigned p = 0, want = KSEL, cls = NPTS;
    int s = 32;
    bool early = false;
    while (s > 0) {
        --s;
        const unsigned p2 = p << 1;
        unsigned cnt = 0;
        #pragma unroll
        for (int i = 0; i < PPL; ++i) cnt += ((key[i] >> s) == p2) ? 1u : 0u;
        unsigned total = 0;
        #pragma unroll
        for (int j = 0; j < 5; ++j)
            total += (unsigned)__popcll(__ballot((cnt >> j) & 1u)) << j;
        if (want <= total) { p = p2;        cls  = total; }
        else               { want -= total; p = p2 | 1u;  cls -= total; }
        if (cls == want) { early = true; break; }
    }

    // ---- phase 3: selection flags. bit i => point (64*i + lane). ----
    unsigned selmask = 0;
    if (early) {
        #pragma unroll
        for (int i = 0; i < PPL; ++i)
            if ((key[i] >> s) <= p) selmask |= (1u << i);
    } else {
        const unsigned kth = p;
        unsigned run_tot = 0;   // stable lowest-index ties: index = 64*i + lane
        #pragma unroll
        for (int i = 0; i < PPL; ++i) {
            const bool eq = (key[i] == kth);
            const unsigned long long bal = __ballot(eq);
            const bool sel_eq = eq && (run_tot + mbcnt64(bal)) < want;
            if (key[i] < kth || sel_eq) selmask |= (1u << i);
            run_tot += (unsigned)__popcll(bal);
        }
    }

    // ---- phase 4 ----
    if (zfirst) {
        // zeros already written; store ONLY the selected points (~1/lane, 12 B).
        // vmcnt(0) guarantees same-address ordering vs the zero-stores (which
        // retired during the ~2000-cycle select); lines still dirty in L2.
        asm volatile("s_waitcnt vmcnt(0)" ::: "memory");
        unsigned sm = selmask;
        while (sm) {
            const int i = __builtin_ctz(sm);
            sm &= sm - 1u;
            const int q = 64 * i + lane;
            const float* pp = base  + 3 * q;   // L1/L2-hot
            float*       op = obase + 3 * q;
            op[0] = pp[0];
            op[1] = pp[1];
            op[2] = pp[2];
        }
    } else {
        // full-row masked store, fully coalesced (round-5 path)
        const f32x4* src4 = reinterpret_cast<const f32x4*>(base);
        #pragma unroll
        for (int j = 0; j < 12; ++j) {
            const int      m  = 64 * j + lane;
            const f32x4    g  = src4[m];
            const unsigned e0 = 4u * (unsigned)m;
            const unsigned q  = e0 / 3u;
            const unsigned u  = e0 - 3u * q;
            const unsigned sm0 = (unsigned)__shfl((int)selmask, (int)(q & 63u), 64);
            const unsigned sm1 = (unsigned)__shfl((int)selmask, (int)((q + 1u) & 63u), 64);
            const unsigned b0  = (sm0 >> (q >> 6)) & 1u;
            const unsigned b1  = (sm1 >> ((q + 1u) >> 6)) & 1u;
            f32x4 v;
            v.x = b0                    ? g.x : 0.0f;
            v.y = ((u == 2u) ? b1 : b0) ? g.y : 0.0f;
            v.z = ((u == 0u) ? b0 : b1) ? g.z : 0.0f;
            v.w = b1                    ? g.w : 0.0f;
            dst4[m] = v;
        }
    }
}

extern "C" void kernel_launch(void* const* d_in, const int* in_sizes, int n_in,
                              void* d_out, int out_size, void* d_ws, size_t ws_size,
                              hipStream_t stream) {
    const float* pc  = (const float*)d_in[0];  // (B,1024,3)
    const float* tgt = (const float*)d_in[1];  // (B,21,3)
    float*       out = (float*)d_out;          // (B,21,1024,3)

    const int B        = in_sizes[0] / (NPTS * 3);   // 512
    const int total_bt = B * NT;                      // 10752
    const int nblocks  = (total_bt + 3) / 4;          // 2688 (divisible by 8)

    knn_mask_fused_kernel<<<nblocks, BLOCK, 0, stream>>>(pc, tgt, out, total_bt);
}

// Round 8
// 34.868 us; speedup vs baseline: 1.0827x; 1.0827x over previous
//
#include <hip/hip_runtime.h>

constexpr int NPTS  = 1024;   // points per batch
constexpr int NT    = 21;     // targets per batch
constexpr int KSEL  = 64;     // top-k
constexpr int BLOCK = 256;    // 4 waves, 1 wave per (b,t)
constexpr int PPL   = 16;     // points per lane (1024 / 64)
constexpr int NXCD  = 8;

typedef float f32x4 __attribute__((ext_vector_type(4)));

__device__ __forceinline__ unsigned key_of(float d) {
    // monotone float->uint transform (total order matching float <)
    unsigned u = __float_as_uint(d);
    return (u & 0x80000000u) ? ~u : (u | 0x80000000u);
}

__device__ __forceinline__ unsigned mbcnt64(unsigned long long m) {
    unsigned lo = __builtin_amdgcn_mbcnt_lo((unsigned)m, 0u);
    return __builtin_amdgcn_mbcnt_hi((unsigned)(m >> 32), lo);
}

__global__ __launch_bounds__(BLOCK) void knn_mask_fused_kernel(
    const float* __restrict__ pc,   // (B, 1024, 3)
    const float* __restrict__ tgt,  // (B, 21, 3)
    float* __restrict__ out,        // (B, 21, 1024, 3)
    int total_bt)
{
    const int wave = threadIdx.x >> 6;
    const int lane = threadIdx.x & 63;
    // bijective XCD swizzle (gridDim.x divisible by 8)
    const int cpx  = gridDim.x / NXCD;
    const int sbid = ((int)blockIdx.x % NXCD) * cpx + (int)blockIdx.x / NXCD;
    const int bt   = sbid * 4 + wave;
    if (bt >= total_bt) return;          // wave-uniform
    const int b  = bt / NT;
    const int tq = bt % NT;

    const float* base  = pc  + (size_t)b  * (NPTS * 3);
    float*       obase = out + (size_t)bt * (NPTS * 3);

    // ---- phase 0: select-independent zeroing of the whole output row (r6) ----
    {
        f32x4* dst4 = reinterpret_cast<f32x4*>(obase);
        const f32x4 z = {0.0f, 0.0f, 0.0f, 0.0f};
        #pragma unroll
        for (int j = 0; j < 12; ++j) dst4[64 * j + lane] = z;
    }

    // target point (wave-uniform, L1-broadcast)
    const float* tp = tgt + ((size_t)b * NT + tq) * 3;
    const float  t0 = tp[0], t1 = tp[1], t2 = tp[2];
    const float  dt = t0 * t0 + t1 * t1 + t2 * t2;

    // ---- phase 1: strided ownership (lane owns points 64*i + lane) ----
    unsigned key[PPL];
    #pragma unroll
    for (int i = 0; i < PPL; ++i) {
        const float* pp = base + 3 * (64 * i + lane);
        const float p0 = pp[0], p1 = pp[1], p2 = pp[2];
        const float d  = dt + (p0 * p0 + p1 * p1 + p2 * p2)
                            - 2.0f * (t0 * p0 + t1 * p1 + t2 * p2);
        key[i] = key_of(d);
    }

    // ---- phase 2: threshold-form exact select of the KSEL-th smallest ----
    // wave-wide AND/OR: skip common high bits entirely
    unsigned kand = key[0], kor = key[0];
    #pragma unroll
    for (int i = 1; i < PPL; ++i) { kand &= key[i]; kor |= key[i]; }
    #pragma unroll
    for (int off = 32; off > 0; off >>= 1) {
        kand &= (unsigned)__shfl_xor((int)kand, off, 64);
        kor  |= (unsigned)__shfl_xor((int)kor,  off, 64);
    }
    const unsigned dis = kor & ~kand;    // bits where keys disagree

    // invariants: below = #{key < lo}; want = KSEL - below; candidate class
    // = keys with resolved high bits == lo's (a contiguous value range)
    unsigned lo = 0, below = 0, want = KSEL, cls = NPTS;
    bool     early = false;
    unsigned Tsel = 0, kth = 0;

    if (dis == 0u) {
        kth = kand;                       // all 1024 keys identical
    } else {
        const int hb = 31 - __builtin_clz(dis);
        lo = (hb == 31) ? 0u : (kand & (~0u << (hb + 1)));  // common high bits
        for (int s = hb; s >= 0; --s) {
            const unsigned mid = lo | (1u << s);
            // count keys < mid (cheap: 1 cmp + 1 add per key, no shifts)
            unsigned cnt = 0;
            #pragma unroll
            for (int i = 0; i < PPL; ++i) cnt += (key[i] < mid) ? 1u : 0u;
            unsigned c = 0;               // wave total, 5-ballot decompose
            #pragma unroll
            for (int j = 0; j < 5; ++j)
                c += (unsigned)__popcll(__ballot((cnt >> j) & 1u)) << j;
            const unsigned t = c - below; // size of class-0 = [lo, mid)
            if (want <= t) { cls = t; }   // descend into class-0; lo keeps bit s = 0
            else { want -= t; below = c; lo = mid; cls -= t; }
            if (cls == want) {            // whole candidate class selected
                early = true;
                Tsel  = lo + (1u << s);   // class upper bound
                break;
            }
        }
        if (!early) kth = lo;             // all bits resolved; ties at kth
    }

    // ---- phase 3: selection flags. bit i => point (64*i + lane). ----
    unsigned selmask = 0;
    if (early) {
        #pragma unroll
        for (int i = 0; i < PPL; ++i)
            if (key[i] < Tsel) selmask |= (1u << i);
    } else {
        unsigned run_tot = 0;   // stable lowest-index ties: index = 64*i + lane
        #pragma unroll
        for (int i = 0; i < PPL; ++i) {
            const bool eq = (key[i] == kth);
            const unsigned long long bal = __ballot(eq);
            const bool sel_eq = eq && (run_tot + mbcnt64(bal)) < want;
            if (key[i] < kth || sel_eq) selmask |= (1u << i);
            run_tot += (unsigned)__popcll(bal);
        }
    }

    // ---- phase 4: store ONLY the selected points (~1/lane, 12 B each).
    // vmcnt(0) orders vs the phase-0 zero stores (retired long ago); lines
    // still dirty in this XCD's L2 -> value stores merge, HBM sees ~129 MB.
    asm volatile("s_waitcnt vmcnt(0)" ::: "memory");
    unsigned sm = selmask;
    while (sm) {
        const int i = __builtin_ctz(sm);
        sm &= sm - 1u;
        const int q = 64 * i + lane;
        const float* pp = base  + 3 * q;   // L1/L2-hot (read in phase 1)
        float*       op = obase + 3 * q;
        op[0] = pp[0];
        op[1] = pp[1];
        op[2] = pp[2];
    }
}

extern "C" void kernel_launch(void* const* d_in, const int* in_sizes, int n_in,
                              void* d_out, int out_size, void* d_ws, size_t ws_size,
                              hipStream_t stream) {
    const float* pc  = (const float*)d_in[0];  // (B,1024,3)
    const float* tgt = (const float*)d_in[1];  // (B,21,3)
    float*       out = (float*)d_out;          // (B,21,1024,3)

    const int B        = in_sizes[0] / (NPTS * 3);   // 512
    const int total_bt = B * NT;                      // 10752
    const int nblocks  = (total_bt + 3) / 4;          // 2688 (divisible by 8)

    knn_mask_fused_kernel<<<nblocks, BLOCK, 0, stream>>>(pc, tgt, out, total_bt);
}